// Round 14
// baseline (2926.193 us; speedup 1.0000x reference)
//
#include <hip/hip_runtime.h>

#define BDIM 64
#define TDIM 1024
#define IDIM 512
#define HDIM 512
#define G4   2048
#define DSLAB 8
#define SLAB_ELEMS (BDIM * HDIM)          // 32768 u16 = 64 KB
#define GROUP_ELEMS (16 * HDIM)           // 8192 u16 = 16 KB

typedef unsigned short u16;
typedef unsigned int u32;
typedef unsigned long long u64;
typedef __attribute__((ext_vector_type(8))) short short8;
typedef __attribute__((ext_vector_type(4))) float f32x4;

__device__ __forceinline__ u16 f2bf(float f) {
    union { float f; unsigned u; } v; v.f = f;
    unsigned u = v.u;
    return (u16)((u + 0x7fffu + ((u >> 16) & 1u)) >> 16);
}
__device__ __forceinline__ float bf2f(u16 h) {
    union { unsigned u; float f; } v; v.u = ((unsigned)h) << 16;
    return v.f;
}
__device__ __forceinline__ float fsig(float x) {
    float e = __builtin_amdgcn_exp2f(x * -1.4426950408889634f);
    return __builtin_amdgcn_rcpf(1.0f + e);
}
__device__ __forceinline__ float ftanh(float x) {
    float e = __builtin_amdgcn_exp2f(x * -2.8853900817779268f);
    return 2.0f * __builtin_amdgcn_rcpf(1.0f + e) - 1.0f;
}

// ---------------------------------------------------------------------------
// prep: W_hh -> bf16, bias, w_full, hbuf ring init (slab0 zeros, 1..7 poison)
// ---------------------------------------------------------------------------
__global__ void prep_kernel(const float* __restrict__ Whh,
                            const float* __restrict__ bih,
                            const float* __restrict__ bhh,
                            const float* __restrict__ log_phi,
                            const float* __restrict__ gammas,
                            u16* __restrict__ whh_bf,
                            float* __restrict__ bias,
                            float* __restrict__ wfull,
                            u32* __restrict__ hbuf32) {
    int idx = blockIdx.x * 256 + threadIdx.x;
    if (idx < G4 * HDIM) whh_bf[idx] = f2bf(Whh[idx]);
    if (idx < G4) bias[idx] = bih[idx] + bhh[idx];
    if (idx < DSLAB * (SLAB_ELEMS / 2))
        hbuf32[idx] = (idx < (SLAB_ELEMS / 2)) ? 0u : 0xffffffffu;
    if (idx < TDIM) {
        float acc = 0.0f;
        #pragma unroll
        for (int m = 0; m < 15; ++m) {
            float lp = log_phi[m];
            float sp = (lp > 15.0f) ? lp : log1pf(expf(lp));
            acc += sp * cosf((float)idx * gammas[m]);
        }
        wfull[idx] = 0.4f * acc / 15.0f;
    }
}

// ---------------------------------------------------------------------------
// cvt: x (33.55M) and W_ih (1M) fp32 -> bf16, 8 elems/thread
// ---------------------------------------------------------------------------
__global__ void cvt_kernel(const float* __restrict__ X, u16* __restrict__ Xbf,
                           const float* __restrict__ W, u16* __restrict__ Wbf) {
    const size_t NX8 = (size_t)BDIM * TDIM * IDIM / 8;   // 4194304
    const size_t NW8 = (size_t)G4 * IDIM / 8;            // 131072
    size_t g = (size_t)blockIdx.x * 256 + threadIdx.x;
    const float* src; u16* dst; size_t off;
    if (g < NX8) { src = X; dst = Xbf; off = g * 8; }
    else if (g < NX8 + NW8) { src = W; dst = Wbf; off = (g - NX8) * 8; }
    else return;
    float4 v0 = *(const float4*)(src + off);
    float4 v1 = *(const float4*)(src + off + 4);
    short8 u;
    u[0] = (short)f2bf(v0.x); u[1] = (short)f2bf(v0.y);
    u[2] = (short)f2bf(v0.z); u[3] = (short)f2bf(v0.w);
    u[4] = (short)f2bf(v1.x); u[5] = (short)f2bf(v1.y);
    u[6] = (short)f2bf(v1.z); u[7] = (short)f2bf(v1.w);
    *(short8*)(dst + off) = u;
}

// ---------------------------------------------------------------------------
// xproj GEMM (bf16 inputs): [65536 x 2048] = Xbf * Wihbf^T + bias
// Output layout: xproj[t][b][n] bf16.
// ---------------------------------------------------------------------------
__global__ __launch_bounds__(256) void xproj_gemm_bf16(
        const u16* __restrict__ Xbf, const u16* __restrict__ Wihbf,
        const float* __restrict__ bias, u16* __restrict__ xproj) {
    const int tid  = threadIdx.x;
    const int m0   = blockIdx.x * 128;
    const int n0   = blockIdx.y * 128;
    const int lane = tid & 63, w = tid >> 6;
    const int l16  = lane & 15, lhi = lane >> 4;
    const int wr   = w >> 1, wc = w & 1;

    __shared__ u16 As[128 * 64];
    __shared__ u16 Bs[128 * 64];

    f32x4 acc[4][4];
    #pragma unroll
    for (int i = 0; i < 4; ++i)
        #pragma unroll
        for (int j = 0; j < 4; ++j) acc[i][j] = (f32x4){0.f, 0.f, 0.f, 0.f};

    for (int kt = 0; kt < 8; ++kt) {
        const int k0 = kt * 64;
        __syncthreads();
        #pragma unroll
        for (int p = 0; p < 4; ++p) {
            int g = p * 256 + tid;
            int row = g >> 3, oct = g & 7;
            short8 u = *(const short8*)(Xbf + (size_t)(m0 + row) * IDIM + k0 + oct * 8);
            *(short8*)&As[row * 64 + ((oct ^ (row & 7)) * 8)] = u;
        }
        #pragma unroll
        for (int p = 0; p < 4; ++p) {
            int g = p * 256 + tid;
            int row = g >> 3, oct = g & 7;
            short8 u = *(const short8*)(Wihbf + (size_t)(n0 + row) * IDIM + k0 + oct * 8);
            *(short8*)&Bs[row * 64 + ((oct ^ (row & 7)) * 8)] = u;
        }
        __syncthreads();
        #pragma unroll
        for (int ks = 0; ks < 2; ++ks) {
            short8 a[4], b[4];
            #pragma unroll
            for (int ai = 0; ai < 4; ++ai) {
                int row = 64 * wr + 16 * ai + l16;
                int oct = (4 * ks + lhi) ^ (row & 7);
                a[ai] = *(const short8*)&As[row * 64 + oct * 8];
            }
            #pragma unroll
            for (int bi = 0; bi < 4; ++bi) {
                int row = 64 * wc + 16 * bi + l16;
                int oct = (4 * ks + lhi) ^ (row & 7);
                b[bi] = *(const short8*)&Bs[row * 64 + oct * 8];
            }
            #pragma unroll
            for (int ai = 0; ai < 4; ++ai)
                #pragma unroll
                for (int bi = 0; bi < 4; ++bi)
                    acc[ai][bi] = __builtin_amdgcn_mfma_f32_16x16x32_bf16(
                        a[ai], b[bi], acc[ai][bi], 0, 0, 0);
        }
    }
    float bv[4];
    #pragma unroll
    for (int bi = 0; bi < 4; ++bi) bv[bi] = bias[n0 + 64 * wc + 16 * bi + l16];
    #pragma unroll
    for (int ai = 0; ai < 4; ++ai) {
        int grow_base = m0 + 64 * wr + 16 * ai + 4 * lhi;
        #pragma unroll
        for (int bi = 0; bi < 4; ++bi) {
            int gcol = n0 + 64 * wc + 16 * bi + l16;
            #pragma unroll
            for (int r = 0; r < 4; ++r) {
                int grow = grow_base + r;
                int b = grow >> 10;
                int t = grow & 1023;
                xproj[((size_t)t * BDIM + b) * G4 + gcol] =
                    f2bf(acc[ai][bi][r] + bv[bi]);
            }
        }
    }
}

// ---------------------------------------------------------------------------
// xproj GEMM (fp32 inputs) — fallback when ws_size can't host bf16 copies.
// ---------------------------------------------------------------------------
__global__ __launch_bounds__(256) void xproj_gemm(
        const float* __restrict__ X, const float* __restrict__ Wih,
        const float* __restrict__ bias, u16* __restrict__ xproj) {
    const int tid  = threadIdx.x;
    const int m0   = blockIdx.x * 128;
    const int n0   = blockIdx.y * 128;
    const int lane = tid & 63, w = tid >> 6;
    const int l16  = lane & 15, lhi = lane >> 4;
    const int wr   = w >> 1, wc = w & 1;

    __shared__ u16 As[128 * 64];
    __shared__ u16 Bs[128 * 64];

    f32x4 acc[4][4];
    #pragma unroll
    for (int i = 0; i < 4; ++i)
        #pragma unroll
        for (int j = 0; j < 4; ++j) acc[i][j] = (f32x4){0.f, 0.f, 0.f, 0.f};

    for (int kt = 0; kt < 8; ++kt) {
        const int k0 = kt * 64;
        __syncthreads();
        #pragma unroll
        for (int p = 0; p < 4; ++p) {
            int g = p * 256 + tid;
            int row = g >> 3, oct = g & 7;
            const float* src = X + (size_t)(m0 + row) * IDIM + k0 + oct * 8;
            float4 v0 = *(const float4*)src;
            float4 v1 = *(const float4*)(src + 4);
            short8 u;
            u[0] = (short)f2bf(v0.x); u[1] = (short)f2bf(v0.y);
            u[2] = (short)f2bf(v0.z); u[3] = (short)f2bf(v0.w);
            u[4] = (short)f2bf(v1.x); u[5] = (short)f2bf(v1.y);
            u[6] = (short)f2bf(v1.z); u[7] = (short)f2bf(v1.w);
            *(short8*)&As[row * 64 + ((oct ^ (row & 7)) * 8)] = u;
        }
        #pragma unroll
        for (int p = 0; p < 4; ++p) {
            int g = p * 256 + tid;
            int row = g >> 3, oct = g & 7;
            const float* src = Wih + (size_t)(n0 + row) * IDIM + k0 + oct * 8;
            float4 v0 = *(const float4*)src;
            float4 v1 = *(const float4*)(src + 4);
            short8 u;
            u[0] = (short)f2bf(v0.x); u[1] = (short)f2bf(v0.y);
            u[2] = (short)f2bf(v0.z); u[3] = (short)f2bf(v0.w);
            u[4] = (short)f2bf(v1.x); u[5] = (short)f2bf(v1.y);
            u[6] = (short)f2bf(v1.z); u[7] = (short)f2bf(v1.w);
            *(short8*)&Bs[row * 64 + ((oct ^ (row & 7)) * 8)] = u;
        }
        __syncthreads();
        #pragma unroll
        for (int ks = 0; ks < 2; ++ks) {
            short8 a[4], b[4];
            #pragma unroll
            for (int ai = 0; ai < 4; ++ai) {
                int row = 64 * wr + 16 * ai + l16;
                int oct = (4 * ks + lhi) ^ (row & 7);
                a[ai] = *(const short8*)&As[row * 64 + oct * 8];
            }
            #pragma unroll
            for (int bi = 0; bi < 4; ++bi) {
                int row = 64 * wc + 16 * bi + l16;
                int oct = (4 * ks + lhi) ^ (row & 7);
                b[bi] = *(const short8*)&Bs[row * 64 + oct * 8];
            }
            #pragma unroll
            for (int ai = 0; ai < 4; ++ai)
                #pragma unroll
                for (int bi = 0; bi < 4; ++bi)
                    acc[ai][bi] = __builtin_amdgcn_mfma_f32_16x16x32_bf16(
                        a[ai], b[bi], acc[ai][bi], 0, 0, 0);
        }
    }
    float bv[4];
    #pragma unroll
    for (int bi = 0; bi < 4; ++bi) bv[bi] = bias[n0 + 64 * wc + 16 * bi + l16];
    #pragma unroll
    for (int ai = 0; ai < 4; ++ai) {
        int grow_base = m0 + 64 * wr + 16 * ai + 4 * lhi;
        #pragma unroll
        for (int bi = 0; bi < 4; ++bi) {
            int gcol = n0 + 64 * wc + 16 * bi + l16;
            #pragma unroll
            for (int r = 0; r < 4; ++r) {
                int grow = grow_base + r;
                int b = grow >> 10;
                int t = grow & 1023;
                xproj[((size_t)t * BDIM + b) * G4 + gcol] =
                    f2bf(acc[ai][bi][r] + bv[bi]);
            }
        }
    }
}

// ---------------------------------------------------------------------------
// scan v14 = v13 + (a) own-fragment early MFMA before sync#1 (hides straggler
// skew; compile-time switch(w) avoids runtime-indexed Bf[] -> scratch), and
// (b) s_sleep(1) backoff after each failed poll round (cuts L3 poll traffic).
// Protocol (agent-scope L3 exchange, poison slab ring, post-barrier re-poison)
// unchanged from the proven v9/v13.
// ---------------------------------------------------------------------------
__global__ __launch_bounds__(256, 1) void scan_kernel(
        const u16* __restrict__ whh_bf, const float* __restrict__ wfull,
        const u16* __restrict__ xproj, u16* __restrict__ hbuf,
        float* __restrict__ out) {
    const int tid = threadIdx.x;
    const int blk = blockIdx.x;      // 0..63
    const int bg  = blk >> 4;        // 0..3   batch group (16 batches)
    const int cgp = blk & 15;        // 0..15  col group (32 h-cols)
    const int b0  = bg * 16;
    const int c0  = cgp * 32;
    const int lane = tid & 63, w = tid >> 6;
    const int l16 = lane & 15, lhi = lane >> 4;

    __shared__ u16  hfrag[16 * 64 * 8];   // 16 KB
    __shared__ float gates[16 * 128];     //  8 KB
    __shared__ float wt_s[TDIM];          //  4 KB

    for (int i = tid; i < TDIM; i += 256) wt_s[i] = wfull[i];

    short8 Bf0[16], Bf1[16];
    #pragma unroll
    for (int ks = 0; ks < 16; ++ks) {
        int row0 = w * HDIM + c0 + l16;
        int row1 = w * HDIM + c0 + 16 + l16;
        Bf0[ks] = *(const short8*)&whh_bf[(size_t)row0 * HDIM + ks * 32 + lhi * 8];
        Bf1[ks] = *(const short8*)&whh_bf[(size_t)row1 * HDIM + ks * 32 + lhi * 8];
    }

    const int eb = tid >> 4;
    const int j0 = 2 * (tid & 15);
    const int gcol = c0 + j0;
    const int ln_e = eb + 16 * (j0 >> 3);
    const size_t eidx = ((size_t)cgp * 64 + ln_e) * 8 + (j0 & 7);
    float creg0 = 0.f, creg1 = 0.f;
    float hp0 = 0.f, hp1 = 0.f;

    u32 xq0, xq1, xq2, xq3;
    {
        const u16* xb = xproj + (size_t)(b0 + eb) * G4 + gcol;
        xq0 = *(const u32*)(xb + 0 * HDIM);
        xq1 = *(const u32*)(xb + 1 * HDIM);
        xq2 = *(const u32*)(xb + 2 * HDIM);
        xq3 = *(const u32*)(xb + 3 * HDIM);
    }
    __syncthreads();

    for (int t = 0; t < TDIM; ++t) {
        const u16* hsrc = hbuf + (size_t)(t & 7) * SLAB_ELEMS
                               + (size_t)bg * GROUP_ELEMS;

        // ---- wave w polls ONLY its 4 ks fragments; s_sleep(1) backoff ----
        union F { u64 q[2]; short8 s; } A4[4];
        for (;;) {
            u32 bad = 0;
            #pragma unroll
            for (int i = 0; i < 4; ++i) {
                const int ks = 4 * w + i;
                const u64* p = (const u64*)(hsrc + ks * 512 + lane * 8);
                u64 lo = __hip_atomic_load(p, __ATOMIC_RELAXED, __HIP_MEMORY_SCOPE_AGENT);
                u64 hi = __hip_atomic_load(p + 1, __ATOMIC_RELAXED, __HIP_MEMORY_SCOPE_AGENT);
                A4[i].q[0] = lo; A4[i].q[1] = hi;
                bad |= ((u32)lo == 0xffffffffu) | ((u32)(lo >> 32) == 0xffffffffu) |
                       ((u32)hi == 0xffffffffu) | ((u32)(hi >> 32) == 0xffffffffu);
            }
            if (!__any((int)bad)) break;
            __builtin_amdgcn_s_sleep(1);   // ~64cy backoff: cuts poll traffic
        }

        // ---- early vmem issue: drains under compute ----
        if (t > 0) {
            *(float2*)(out + ((size_t)(b0 + eb) * TDIM + (t - 1)) * HDIM + gcol) =
                make_float2(hp0, hp1);
        }
        u32 nx0 = 0, nx1 = 0, nx2 = 0, nx3 = 0;
        if (t + 1 < TDIM) {
            const u16* xb = xproj + (size_t)(t + 1) * BDIM * G4 +
                            (size_t)(b0 + eb) * G4 + gcol;
            nx0 = *(const u32*)(xb + 0 * HDIM);
            nx1 = *(const u32*)(xb + 1 * HDIM);
            nx2 = *(const u32*)(xb + 2 * HDIM);
            nx3 = *(const u32*)(xb + 3 * HDIM);
        }

        // ---- stage own fragments to LDS ----
        #pragma unroll
        for (int i = 0; i < 4; ++i) {
            const int ks = 4 * w + i;
            *(short8*)&hfrag[(ks * 64 + lane) * 8] = A4[i].s;
        }

        // ---- own-fragment early MFMA (register A-frags; before barrier) ----
        f32x4 acc0a = {0.f, 0.f, 0.f, 0.f}, acc0b = {0.f, 0.f, 0.f, 0.f};
        f32x4 acc1a = {0.f, 0.f, 0.f, 0.f}, acc1b = {0.f, 0.f, 0.f, 0.f};
        #define OWN_MFMA(W)                                                               \
            acc0a = __builtin_amdgcn_mfma_f32_16x16x32_bf16(A4[0].s, Bf0[4*W+0], acc0a, 0, 0, 0); \
            acc1a = __builtin_amdgcn_mfma_f32_16x16x32_bf16(A4[0].s, Bf1[4*W+0], acc1a, 0, 0, 0); \
            acc0b = __builtin_amdgcn_mfma_f32_16x16x32_bf16(A4[1].s, Bf0[4*W+1], acc0b, 0, 0, 0); \
            acc1b = __builtin_amdgcn_mfma_f32_16x16x32_bf16(A4[1].s, Bf1[4*W+1], acc1b, 0, 0, 0); \
            acc0a = __builtin_amdgcn_mfma_f32_16x16x32_bf16(A4[2].s, Bf0[4*W+2], acc0a, 0, 0, 0); \
            acc1a = __builtin_amdgcn_mfma_f32_16x16x32_bf16(A4[2].s, Bf1[4*W+2], acc1a, 0, 0, 0); \
            acc0b = __builtin_amdgcn_mfma_f32_16x16x32_bf16(A4[3].s, Bf0[4*W+3], acc0b, 0, 0, 0); \
            acc1b = __builtin_amdgcn_mfma_f32_16x16x32_bf16(A4[3].s, Bf1[4*W+3], acc1b, 0, 0, 0);
        switch (w) {
            case 0: { OWN_MFMA(0) } break;
            case 1: { OWN_MFMA(1) } break;
            case 2: { OWN_MFMA(2) } break;
            default:{ OWN_MFMA(3) } break;
        }
        #undef OWN_MFMA

        __syncthreads();
        // whole block verified slab t complete -> slab t-1 readers done
        if (t > 0) {
            __hip_atomic_store(
                (u32*)(hbuf + (size_t)((t - 1) & 7) * SLAB_ELEMS +
                       (size_t)bg * GROUP_ELEMS + eidx), 0xffffffffu,
                __ATOMIC_RELAXED, __HIP_MEMORY_SCOPE_AGENT);
        }

        // ---- remaining 12 fragments from LDS ----
        #pragma unroll
        for (int ks = 0; ks < 16; ++ks) {
            if ((ks >> 2) == w) continue;   // own: already accumulated
            short8 a = *(const short8*)&hfrag[(ks * 64 + lane) * 8];
            if (ks & 1) {
                acc0b = __builtin_amdgcn_mfma_f32_16x16x32_bf16(a, Bf0[ks], acc0b, 0, 0, 0);
                acc1b = __builtin_amdgcn_mfma_f32_16x16x32_bf16(a, Bf1[ks], acc1b, 0, 0, 0);
            } else {
                acc0a = __builtin_amdgcn_mfma_f32_16x16x32_bf16(a, Bf0[ks], acc0a, 0, 0, 0);
                acc1a = __builtin_amdgcn_mfma_f32_16x16x32_bf16(a, Bf1[ks], acc1a, 0, 0, 0);
            }
        }
        f32x4 acc0 = acc0a + acc0b;
        f32x4 acc1 = acc1a + acc1b;
        #pragma unroll
        for (int r = 0; r < 4; ++r) {
            gates[(4 * lhi + r) * 128 + w * 32 + l16]      = acc0[r];
            gates[(4 * lhi + r) * 128 + w * 32 + 16 + l16] = acc1[r];
        }
        __syncthreads();

        // ---- elementwise LSTM + zeta ----
        const float wt = wt_s[t];
        float x0 = bf2f((u16)(xq0 & 0xffff)), x1 = bf2f((u16)(xq0 >> 16));
        float f0 = bf2f((u16)(xq1 & 0xffff)), f1 = bf2f((u16)(xq1 >> 16));
        float g0 = bf2f((u16)(xq2 & 0xffff)), g1 = bf2f((u16)(xq2 >> 16));
        float o0 = bf2f((u16)(xq3 & 0xffff)), o1 = bf2f((u16)(xq3 >> 16));

        float gi0 = gates[eb * 128 + 0 * 32 + j0]     + x0;
        float gi1 = gates[eb * 128 + 0 * 32 + j0 + 1] + x1;
        float gf0 = gates[eb * 128 + 1 * 32 + j0]     + f0;
        float gf1 = gates[eb * 128 + 1 * 32 + j0 + 1] + f1;
        float gg0 = gates[eb * 128 + 2 * 32 + j0]     + g0;
        float gg1 = gates[eb * 128 + 2 * 32 + j0 + 1] + g1;
        float go0 = gates[eb * 128 + 3 * 32 + j0]     + o0;
        float go1 = gates[eb * 128 + 3 * 32 + j0 + 1] + o1;

        float cn0 = fsig(gf0) * creg0 + fsig(gi0) * ftanh(gg0);
        float cn1 = fsig(gf1) * creg1 + fsig(gi1) * ftanh(gg1);
        float ho0 = fsig(go0) * ftanh(cn0) + wt * hp0;
        float ho1 = fsig(go1) * ftanh(cn1) + wt * hp1;
        creg0 = cn0; creg1 = cn1;
        hp0 = ho0; hp1 = ho1;

        // ---- publish h[t+1] ----
        u32 hw = (u32)f2bf(ho0) | ((u32)f2bf(ho1) << 16);
        __hip_atomic_store(
            (u32*)(hbuf + (size_t)((t + 1) & 7) * SLAB_ELEMS +
                   (size_t)bg * GROUP_ELEMS + eidx), hw,
            __ATOMIC_RELAXED, __HIP_MEMORY_SCOPE_AGENT);

        xq0 = nx0; xq1 = nx1; xq2 = nx2; xq3 = nx3;
    }

    // ---- tail ----
    *(float2*)(out + ((size_t)(b0 + eb) * TDIM + (TDIM - 1)) * HDIM + gcol) =
        make_float2(hp0, hp1);
    size_t base = (size_t)BDIM * TDIM * HDIM;
    *(float2*)(out + base + (size_t)(b0 + eb) * HDIM + gcol) =
        make_float2(hp0, hp1);
    *(float2*)(out + base + (size_t)BDIM * HDIM + (size_t)(b0 + eb) * HDIM + gcol) =
        make_float2(creg0, creg1);
}

// ---------------------------------------------------------------------------
extern "C" void kernel_launch(void* const* d_in, const int* in_sizes, int n_in,
                              void* d_out, int out_size, void* d_ws, size_t ws_size,
                              hipStream_t stream) {
    const float* x       = (const float*)d_in[0];
    const float* Wih     = (const float*)d_in[1];
    const float* Whh     = (const float*)d_in[2];
    const float* bih     = (const float*)d_in[3];
    const float* bhh     = (const float*)d_in[4];
    const float* log_phi = (const float*)d_in[5];
    const float* gammas  = (const float*)d_in[6];
    float* out = (float*)d_out;

    char* ws = (char*)d_ws;
    u16*   whh_bf = (u16*)(ws);                               // 2 MB
    float* bias   = (float*)(ws + (2u << 20));                // 8 KB
    float* wfull  = (float*)(ws + (2u << 20) + 8192);         // 4 KB
    u16*   hbuf   = (u16*)(ws + (3u << 20));                  // 512 KB ring
    u16*   xproj  = (u16*)(ws + (4u << 20));                  // 256 MB -> ends 260MB
    u16*   x_bf   = (u16*)(ws + (260ull << 20));              // 64 MB  -> ends 324MB
    u16*   wih_bf = (u16*)(ws + (324ull << 20));              // 2 MB   -> ends 326MB
    const bool bf16path = ws_size >= (326ull << 20);

    prep_kernel<<<dim3(4096), dim3(256), 0, stream>>>(
        Whh, bih, bhh, log_phi, gammas, whh_bf, bias, wfull, (u32*)hbuf);

    if (bf16path) {
        cvt_kernel<<<dim3(16896), dim3(256), 0, stream>>>(x, x_bf, Wih, wih_bf);
        xproj_gemm_bf16<<<dim3(512, 16), dim3(256), 0, stream>>>(
            x_bf, wih_bf, bias, xproj);
    } else {
        xproj_gemm<<<dim3(512, 16), dim3(256), 0, stream>>>(x, Wih, bias, xproj);
    }

    scan_kernel<<<dim3(64), dim3(256), 0, stream>>>(
        whh_bf, wfull, xproj, hbuf, out);
}

// Round 15
// 2542.530 us; speedup vs baseline: 1.1509x; 1.1509x over previous
//
#include <hip/hip_runtime.h>

#define BDIM 64
#define TDIM 1024
#define IDIM 512
#define HDIM 512
#define G4   2048
#define DSLAB 8
#define SLAB_ELEMS (BDIM * HDIM)          // 32768 u16 = 64 KB
#define GROUP_ELEMS (16 * HDIM)           // 8192 u16 = 16 KB

typedef unsigned short u16;
typedef unsigned int u32;
typedef unsigned long long u64;
typedef __attribute__((ext_vector_type(8))) short short8;
typedef __attribute__((ext_vector_type(4))) float f32x4;

__device__ __forceinline__ u16 f2bf(float f) {
    union { float f; unsigned u; } v; v.f = f;
    unsigned u = v.u;
    return (u16)((u + 0x7fffu + ((u >> 16) & 1u)) >> 16);
}
__device__ __forceinline__ float bf2f(u16 h) {
    union { unsigned u; float f; } v; v.u = ((unsigned)h) << 16;
    return v.f;
}
__device__ __forceinline__ float fsig(float x) {
    float e = __builtin_amdgcn_exp2f(x * -1.4426950408889634f);
    return __builtin_amdgcn_rcpf(1.0f + e);
}
__device__ __forceinline__ float ftanh(float x) {
    float e = __builtin_amdgcn_exp2f(x * -2.8853900817779268f);
    return 2.0f * __builtin_amdgcn_rcpf(1.0f + e) - 1.0f;
}

// ---------------------------------------------------------------------------
// prep: W_hh -> bf16, bias, w_full, hbuf ring init (slab0 zeros, 1..7 poison)
// ---------------------------------------------------------------------------
__global__ void prep_kernel(const float* __restrict__ Whh,
                            const float* __restrict__ bih,
                            const float* __restrict__ bhh,
                            const float* __restrict__ log_phi,
                            const float* __restrict__ gammas,
                            u16* __restrict__ whh_bf,
                            float* __restrict__ bias,
                            float* __restrict__ wfull,
                            u32* __restrict__ hbuf32) {
    int idx = blockIdx.x * 256 + threadIdx.x;
    if (idx < G4 * HDIM) whh_bf[idx] = f2bf(Whh[idx]);
    if (idx < G4) bias[idx] = bih[idx] + bhh[idx];
    if (idx < DSLAB * (SLAB_ELEMS / 2))
        hbuf32[idx] = (idx < (SLAB_ELEMS / 2)) ? 0u : 0xffffffffu;
    if (idx < TDIM) {
        float acc = 0.0f;
        #pragma unroll
        for (int m = 0; m < 15; ++m) {
            float lp = log_phi[m];
            float sp = (lp > 15.0f) ? lp : log1pf(expf(lp));
            acc += sp * cosf((float)idx * gammas[m]);
        }
        wfull[idx] = 0.4f * acc / 15.0f;
    }
}

// ---------------------------------------------------------------------------
// cvt: x (33.55M) and W_ih (1M) fp32 -> bf16, 8 elems/thread
// ---------------------------------------------------------------------------
__global__ void cvt_kernel(const float* __restrict__ X, u16* __restrict__ Xbf,
                           const float* __restrict__ W, u16* __restrict__ Wbf) {
    const size_t NX8 = (size_t)BDIM * TDIM * IDIM / 8;   // 4194304
    const size_t NW8 = (size_t)G4 * IDIM / 8;            // 131072
    size_t g = (size_t)blockIdx.x * 256 + threadIdx.x;
    const float* src; u16* dst; size_t off;
    if (g < NX8) { src = X; dst = Xbf; off = g * 8; }
    else if (g < NX8 + NW8) { src = W; dst = Wbf; off = (g - NX8) * 8; }
    else return;
    float4 v0 = *(const float4*)(src + off);
    float4 v1 = *(const float4*)(src + off + 4);
    short8 u;
    u[0] = (short)f2bf(v0.x); u[1] = (short)f2bf(v0.y);
    u[2] = (short)f2bf(v0.z); u[3] = (short)f2bf(v0.w);
    u[4] = (short)f2bf(v1.x); u[5] = (short)f2bf(v1.y);
    u[6] = (short)f2bf(v1.z); u[7] = (short)f2bf(v1.w);
    *(short8*)(dst + off) = u;
}

// ---------------------------------------------------------------------------
// xproj GEMM (bf16 inputs): [65536 x 2048] = Xbf * Wihbf^T + bias
// Output layout: xproj[t][b][n] bf16.
// ---------------------------------------------------------------------------
__global__ __launch_bounds__(256) void xproj_gemm_bf16(
        const u16* __restrict__ Xbf, const u16* __restrict__ Wihbf,
        const float* __restrict__ bias, u16* __restrict__ xproj) {
    const int tid  = threadIdx.x;
    const int m0   = blockIdx.x * 128;
    const int n0   = blockIdx.y * 128;
    const int lane = tid & 63, w = tid >> 6;
    const int l16  = lane & 15, lhi = lane >> 4;
    const int wr   = w >> 1, wc = w & 1;

    __shared__ u16 As[128 * 64];
    __shared__ u16 Bs[128 * 64];

    f32x4 acc[4][4];
    #pragma unroll
    for (int i = 0; i < 4; ++i)
        #pragma unroll
        for (int j = 0; j < 4; ++j) acc[i][j] = (f32x4){0.f, 0.f, 0.f, 0.f};

    for (int kt = 0; kt < 8; ++kt) {
        const int k0 = kt * 64;
        __syncthreads();
        #pragma unroll
        for (int p = 0; p < 4; ++p) {
            int g = p * 256 + tid;
            int row = g >> 3, oct = g & 7;
            short8 u = *(const short8*)(Xbf + (size_t)(m0 + row) * IDIM + k0 + oct * 8);
            *(short8*)&As[row * 64 + ((oct ^ (row & 7)) * 8)] = u;
        }
        #pragma unroll
        for (int p = 0; p < 4; ++p) {
            int g = p * 256 + tid;
            int row = g >> 3, oct = g & 7;
            short8 u = *(const short8*)(Wihbf + (size_t)(n0 + row) * IDIM + k0 + oct * 8);
            *(short8*)&Bs[row * 64 + ((oct ^ (row & 7)) * 8)] = u;
        }
        __syncthreads();
        #pragma unroll
        for (int ks = 0; ks < 2; ++ks) {
            short8 a[4], b[4];
            #pragma unroll
            for (int ai = 0; ai < 4; ++ai) {
                int row = 64 * wr + 16 * ai + l16;
                int oct = (4 * ks + lhi) ^ (row & 7);
                a[ai] = *(const short8*)&As[row * 64 + oct * 8];
            }
            #pragma unroll
            for (int bi = 0; bi < 4; ++bi) {
                int row = 64 * wc + 16 * bi + l16;
                int oct = (4 * ks + lhi) ^ (row & 7);
                b[bi] = *(const short8*)&Bs[row * 64 + oct * 8];
            }
            #pragma unroll
            for (int ai = 0; ai < 4; ++ai)
                #pragma unroll
                for (int bi = 0; bi < 4; ++bi)
                    acc[ai][bi] = __builtin_amdgcn_mfma_f32_16x16x32_bf16(
                        a[ai], b[bi], acc[ai][bi], 0, 0, 0);
        }
    }
    float bv[4];
    #pragma unroll
    for (int bi = 0; bi < 4; ++bi) bv[bi] = bias[n0 + 64 * wc + 16 * bi + l16];
    #pragma unroll
    for (int ai = 0; ai < 4; ++ai) {
        int grow_base = m0 + 64 * wr + 16 * ai + 4 * lhi;
        #pragma unroll
        for (int bi = 0; bi < 4; ++bi) {
            int gcol = n0 + 64 * wc + 16 * bi + l16;
            #pragma unroll
            for (int r = 0; r < 4; ++r) {
                int grow = grow_base + r;
                int b = grow >> 10;
                int t = grow & 1023;
                xproj[((size_t)t * BDIM + b) * G4 + gcol] =
                    f2bf(acc[ai][bi][r] + bv[bi]);
            }
        }
    }
}

// ---------------------------------------------------------------------------
// xproj GEMM (fp32 inputs) — fallback when ws_size can't host bf16 copies.
// ---------------------------------------------------------------------------
__global__ __launch_bounds__(256) void xproj_gemm(
        const float* __restrict__ X, const float* __restrict__ Wih,
        const float* __restrict__ bias, u16* __restrict__ xproj) {
    const int tid  = threadIdx.x;
    const int m0   = blockIdx.x * 128;
    const int n0   = blockIdx.y * 128;
    const int lane = tid & 63, w = tid >> 6;
    const int l16  = lane & 15, lhi = lane >> 4;
    const int wr   = w >> 1, wc = w & 1;

    __shared__ u16 As[128 * 64];
    __shared__ u16 Bs[128 * 64];

    f32x4 acc[4][4];
    #pragma unroll
    for (int i = 0; i < 4; ++i)
        #pragma unroll
        for (int j = 0; j < 4; ++j) acc[i][j] = (f32x4){0.f, 0.f, 0.f, 0.f};

    for (int kt = 0; kt < 8; ++kt) {
        const int k0 = kt * 64;
        __syncthreads();
        #pragma unroll
        for (int p = 0; p < 4; ++p) {
            int g = p * 256 + tid;
            int row = g >> 3, oct = g & 7;
            const float* src = X + (size_t)(m0 + row) * IDIM + k0 + oct * 8;
            float4 v0 = *(const float4*)src;
            float4 v1 = *(const float4*)(src + 4);
            short8 u;
            u[0] = (short)f2bf(v0.x); u[1] = (short)f2bf(v0.y);
            u[2] = (short)f2bf(v0.z); u[3] = (short)f2bf(v0.w);
            u[4] = (short)f2bf(v1.x); u[5] = (short)f2bf(v1.y);
            u[6] = (short)f2bf(v1.z); u[7] = (short)f2bf(v1.w);
            *(short8*)&As[row * 64 + ((oct ^ (row & 7)) * 8)] = u;
        }
        #pragma unroll
        for (int p = 0; p < 4; ++p) {
            int g = p * 256 + tid;
            int row = g >> 3, oct = g & 7;
            const float* src = Wih + (size_t)(n0 + row) * IDIM + k0 + oct * 8;
            float4 v0 = *(const float4*)src;
            float4 v1 = *(const float4*)(src + 4);
            short8 u;
            u[0] = (short)f2bf(v0.x); u[1] = (short)f2bf(v0.y);
            u[2] = (short)f2bf(v0.z); u[3] = (short)f2bf(v0.w);
            u[4] = (short)f2bf(v1.x); u[5] = (short)f2bf(v1.y);
            u[6] = (short)f2bf(v1.z); u[7] = (short)f2bf(v1.w);
            *(short8*)&Bs[row * 64 + ((oct ^ (row & 7)) * 8)] = u;
        }
        __syncthreads();
        #pragma unroll
        for (int ks = 0; ks < 2; ++ks) {
            short8 a[4], b[4];
            #pragma unroll
            for (int ai = 0; ai < 4; ++ai) {
                int row = 64 * wr + 16 * ai + l16;
                int oct = (4 * ks + lhi) ^ (row & 7);
                a[ai] = *(const short8*)&As[row * 64 + oct * 8];
            }
            #pragma unroll
            for (int bi = 0; bi < 4; ++bi) {
                int row = 64 * wc + 16 * bi + l16;
                int oct = (4 * ks + lhi) ^ (row & 7);
                b[bi] = *(const short8*)&Bs[row * 64 + oct * 8];
            }
            #pragma unroll
            for (int ai = 0; ai < 4; ++ai)
                #pragma unroll
                for (int bi = 0; bi < 4; ++bi)
                    acc[ai][bi] = __builtin_amdgcn_mfma_f32_16x16x32_bf16(
                        a[ai], b[bi], acc[ai][bi], 0, 0, 0);
        }
    }
    float bv[4];
    #pragma unroll
    for (int bi = 0; bi < 4; ++bi) bv[bi] = bias[n0 + 64 * wc + 16 * bi + l16];
    #pragma unroll
    for (int ai = 0; ai < 4; ++ai) {
        int grow_base = m0 + 64 * wr + 16 * ai + 4 * lhi;
        #pragma unroll
        for (int bi = 0; bi < 4; ++bi) {
            int gcol = n0 + 64 * wc + 16 * bi + l16;
            #pragma unroll
            for (int r = 0; r < 4; ++r) {
                int grow = grow_base + r;
                int b = grow >> 10;
                int t = grow & 1023;
                xproj[((size_t)t * BDIM + b) * G4 + gcol] =
                    f2bf(acc[ai][bi][r] + bv[bi]);
            }
        }
    }
}

// ---------------------------------------------------------------------------
// scan v15 = v13 EXACTLY (best measured: 2.305 ms). Agent-scope L3 exchange,
// poison slab ring, wave-split polling, early vmem issue after detect,
// post-barrier re-poison, split MFMA accumulator chains. Nothing between
// poll-detect and the staging barrier except the 4 LDS writes + early vmem
// issues (R13's early-MFMA/backoff regressed; reverted).
// ---------------------------------------------------------------------------
__global__ __launch_bounds__(256, 1) void scan_kernel(
        const u16* __restrict__ whh_bf, const float* __restrict__ wfull,
        const u16* __restrict__ xproj, u16* __restrict__ hbuf,
        float* __restrict__ out) {
    const int tid = threadIdx.x;
    const int blk = blockIdx.x;      // 0..63
    const int bg  = blk >> 4;        // 0..3   batch group (16 batches)
    const int cgp = blk & 15;        // 0..15  col group (32 h-cols)
    const int b0  = bg * 16;
    const int c0  = cgp * 32;
    const int lane = tid & 63, w = tid >> 6;
    const int l16 = lane & 15, lhi = lane >> 4;

    __shared__ u16  hfrag[16 * 64 * 8];   // 16 KB
    __shared__ float gates[16 * 128];     //  8 KB
    __shared__ float wt_s[TDIM];          //  4 KB

    for (int i = tid; i < TDIM; i += 256) wt_s[i] = wfull[i];

    short8 Bf0[16], Bf1[16];
    #pragma unroll
    for (int ks = 0; ks < 16; ++ks) {
        int row0 = w * HDIM + c0 + l16;
        int row1 = w * HDIM + c0 + 16 + l16;
        Bf0[ks] = *(const short8*)&whh_bf[(size_t)row0 * HDIM + ks * 32 + lhi * 8];
        Bf1[ks] = *(const short8*)&whh_bf[(size_t)row1 * HDIM + ks * 32 + lhi * 8];
    }

    const int eb = tid >> 4;
    const int j0 = 2 * (tid & 15);
    const int gcol = c0 + j0;
    const int ln_e = eb + 16 * (j0 >> 3);
    const size_t eidx = ((size_t)cgp * 64 + ln_e) * 8 + (j0 & 7);
    float creg0 = 0.f, creg1 = 0.f;
    float hp0 = 0.f, hp1 = 0.f;

    u32 xq0, xq1, xq2, xq3;
    {
        const u16* xb = xproj + (size_t)(b0 + eb) * G4 + gcol;
        xq0 = *(const u32*)(xb + 0 * HDIM);
        xq1 = *(const u32*)(xb + 1 * HDIM);
        xq2 = *(const u32*)(xb + 2 * HDIM);
        xq3 = *(const u32*)(xb + 3 * HDIM);
    }
    __syncthreads();

    for (int t = 0; t < TDIM; ++t) {
        const u16* hsrc = hbuf + (size_t)(t & 7) * SLAB_ELEMS
                               + (size_t)bg * GROUP_ELEMS;

        // ---- wave w polls ONLY its 4 ks fragments until poison-free ----
        union F { u64 q[2]; short8 s; } A4[4];
        for (;;) {
            u32 bad = 0;
            #pragma unroll
            for (int i = 0; i < 4; ++i) {
                const int ks = 4 * w + i;
                const u64* p = (const u64*)(hsrc + ks * 512 + lane * 8);
                u64 lo = __hip_atomic_load(p, __ATOMIC_RELAXED, __HIP_MEMORY_SCOPE_AGENT);
                u64 hi = __hip_atomic_load(p + 1, __ATOMIC_RELAXED, __HIP_MEMORY_SCOPE_AGENT);
                A4[i].q[0] = lo; A4[i].q[1] = hi;
                bad |= ((u32)lo == 0xffffffffu) | ((u32)(lo >> 32) == 0xffffffffu) |
                       ((u32)hi == 0xffffffffu) | ((u32)(hi >> 32) == 0xffffffffu);
            }
            if (!__any((int)bad)) break;
        }

        // ---- early vmem issue (non-protocol): drains under compute ----
        if (t > 0) {
            *(float2*)(out + ((size_t)(b0 + eb) * TDIM + (t - 1)) * HDIM + gcol) =
                make_float2(hp0, hp1);
        }
        u32 nx0 = 0, nx1 = 0, nx2 = 0, nx3 = 0;
        if (t + 1 < TDIM) {
            const u16* xb = xproj + (size_t)(t + 1) * BDIM * G4 +
                            (size_t)(b0 + eb) * G4 + gcol;
            nx0 = *(const u32*)(xb + 0 * HDIM);
            nx1 = *(const u32*)(xb + 1 * HDIM);
            nx2 = *(const u32*)(xb + 2 * HDIM);
            nx3 = *(const u32*)(xb + 3 * HDIM);
        }

        // ---- stage own fragments to LDS ----
        #pragma unroll
        for (int i = 0; i < 4; ++i) {
            const int ks = 4 * w + i;
            *(short8*)&hfrag[(ks * 64 + lane) * 8] = A4[i].s;
        }
        __syncthreads();
        // whole block verified slab t complete -> slab t-1 readers done
        if (t > 0) {
            __hip_atomic_store(
                (u32*)(hbuf + (size_t)((t - 1) & 7) * SLAB_ELEMS +
                       (size_t)bg * GROUP_ELEMS + eidx), 0xffffffffu,
                __ATOMIC_RELAXED, __HIP_MEMORY_SCOPE_AGENT);
        }

        // ---- gates GEMM tile: A from LDS, B from regs; 2x 8-deep chains ----
        f32x4 acc0a = {0.f, 0.f, 0.f, 0.f}, acc0b = {0.f, 0.f, 0.f, 0.f};
        f32x4 acc1a = {0.f, 0.f, 0.f, 0.f}, acc1b = {0.f, 0.f, 0.f, 0.f};
        #pragma unroll
        for (int ks = 0; ks < 8; ++ks) {
            short8 a  = *(const short8*)&hfrag[(ks * 64 + lane) * 8];
            short8 a2 = *(const short8*)&hfrag[((ks + 8) * 64 + lane) * 8];
            acc0a = __builtin_amdgcn_mfma_f32_16x16x32_bf16(a,  Bf0[ks],     acc0a, 0, 0, 0);
            acc1a = __builtin_amdgcn_mfma_f32_16x16x32_bf16(a,  Bf1[ks],     acc1a, 0, 0, 0);
            acc0b = __builtin_amdgcn_mfma_f32_16x16x32_bf16(a2, Bf0[ks + 8], acc0b, 0, 0, 0);
            acc1b = __builtin_amdgcn_mfma_f32_16x16x32_bf16(a2, Bf1[ks + 8], acc1b, 0, 0, 0);
        }
        f32x4 acc0 = acc0a + acc0b;
        f32x4 acc1 = acc1a + acc1b;
        #pragma unroll
        for (int r = 0; r < 4; ++r) {
            gates[(4 * lhi + r) * 128 + w * 32 + l16]      = acc0[r];
            gates[(4 * lhi + r) * 128 + w * 32 + 16 + l16] = acc1[r];
        }
        __syncthreads();

        // ---- elementwise LSTM + zeta ----
        const float wt = wt_s[t];
        float x0 = bf2f((u16)(xq0 & 0xffff)), x1 = bf2f((u16)(xq0 >> 16));
        float f0 = bf2f((u16)(xq1 & 0xffff)), f1 = bf2f((u16)(xq1 >> 16));
        float g0 = bf2f((u16)(xq2 & 0xffff)), g1 = bf2f((u16)(xq2 >> 16));
        float o0 = bf2f((u16)(xq3 & 0xffff)), o1 = bf2f((u16)(xq3 >> 16));

        float gi0 = gates[eb * 128 + 0 * 32 + j0]     + x0;
        float gi1 = gates[eb * 128 + 0 * 32 + j0 + 1] + x1;
        float gf0 = gates[eb * 128 + 1 * 32 + j0]     + f0;
        float gf1 = gates[eb * 128 + 1 * 32 + j0 + 1] + f1;
        float gg0 = gates[eb * 128 + 2 * 32 + j0]     + g0;
        float gg1 = gates[eb * 128 + 2 * 32 + j0 + 1] + g1;
        float go0 = gates[eb * 128 + 3 * 32 + j0]     + o0;
        float go1 = gates[eb * 128 + 3 * 32 + j0 + 1] + o1;

        float cn0 = fsig(gf0) * creg0 + fsig(gi0) * ftanh(gg0);
        float cn1 = fsig(gf1) * creg1 + fsig(gi1) * ftanh(gg1);
        float ho0 = fsig(go0) * ftanh(cn0) + wt * hp0;
        float ho1 = fsig(go1) * ftanh(cn1) + wt * hp1;
        creg0 = cn0; creg1 = cn1;
        hp0 = ho0; hp1 = ho1;

        // ---- publish h[t+1]: the ONLY vmem op before the next poll ----
        u32 hw = (u32)f2bf(ho0) | ((u32)f2bf(ho1) << 16);
        __hip_atomic_store(
            (u32*)(hbuf + (size_t)((t + 1) & 7) * SLAB_ELEMS +
                   (size_t)bg * GROUP_ELEMS + eidx), hw,
            __ATOMIC_RELAXED, __HIP_MEMORY_SCOPE_AGENT);

        xq0 = nx0; xq1 = nx1; xq2 = nx2; xq3 = nx3;
    }

    // ---- tail ----
    *(float2*)(out + ((size_t)(b0 + eb) * TDIM + (TDIM - 1)) * HDIM + gcol) =
        make_float2(hp0, hp1);
    size_t base = (size_t)BDIM * TDIM * HDIM;
    *(float2*)(out + base + (size_t)(b0 + eb) * HDIM + gcol) =
        make_float2(hp0, hp1);
    *(float2*)(out + base + (size_t)BDIM * HDIM + (size_t)(b0 + eb) * HDIM + gcol) =
        make_float2(creg0, creg1);
}

// ---------------------------------------------------------------------------
extern "C" void kernel_launch(void* const* d_in, const int* in_sizes, int n_in,
                              void* d_out, int out_size, void* d_ws, size_t ws_size,
                              hipStream_t stream) {
    const float* x       = (const float*)d_in[0];
    const float* Wih     = (const float*)d_in[1];
    const float* Whh     = (const float*)d_in[2];
    const float* bih     = (const float*)d_in[3];
    const float* bhh     = (const float*)d_in[4];
    const float* log_phi = (const float*)d_in[5];
    const float* gammas  = (const float*)d_in[6];
    float* out = (float*)d_out;

    char* ws = (char*)d_ws;
    u16*   whh_bf = (u16*)(ws);                               // 2 MB
    float* bias   = (float*)(ws + (2u << 20));                // 8 KB
    float* wfull  = (float*)(ws + (2u << 20) + 8192);         // 4 KB
    u16*   hbuf   = (u16*)(ws + (3u << 20));                  // 512 KB ring
    u16*   xproj  = (u16*)(ws + (4u << 20));                  // 256 MB -> ends 260MB
    u16*   x_bf   = (u16*)(ws + (260ull << 20));              // 64 MB  -> ends 324MB
    u16*   wih_bf = (u16*)(ws + (324ull << 20));              // 2 MB   -> ends 326MB
    const bool bf16path = ws_size >= (326ull << 20);

    prep_kernel<<<dim3(4096), dim3(256), 0, stream>>>(
        Whh, bih, bhh, log_phi, gammas, whh_bf, bias, wfull, (u32*)hbuf);

    if (bf16path) {
        cvt_kernel<<<dim3(16896), dim3(256), 0, stream>>>(x, x_bf, Wih, wih_bf);
        xproj_gemm_bf16<<<dim3(512, 16), dim3(256), 0, stream>>>(
            x_bf, wih_bf, bias, xproj);
    } else {
        xproj_gemm<<<dim3(512, 16), dim3(256), 0, stream>>>(x, Wih, bias, xproj);
    }

    scan_kernel<<<dim3(64), dim3(256), 0, stream>>>(
        whh_bf, wfull, xproj, hbuf, out);
}